// Round 11
// baseline (113.787 us; speedup 1.0000x reference)
//
#include <hip/hip_runtime.h>

typedef __attribute__((ext_vector_type(4))) _Float16 half4;
typedef __attribute__((ext_vector_type(4))) float floatx4;
typedef __attribute__((ext_vector_type(2))) float float2v;
typedef __attribute__((ext_vector_type(2))) unsigned uint2v;

#define NH 8
#define CHUNKS 4

#define TSCL 2.8853900817779268f    // 2*log2(e)
#define NSCL (-2.0f * TSCL)         // feed-r hidden weight scale
#define OSCL (-1.4426950408889634f) // -log2(e)
#define UNSC 4.8828125e-4f          // 2^-11

struct R4   { float2v a, b; };                    // 4 r-values (packed pairs)
struct Act4 { unsigned hi01, hi23, lo01, lo23; }; // split B-fragment halves

// r_i = 1/(2^min(s_i,25)+1): one rcp (+Newton) for 4 acts; packed pair ops
// where VOP3P f32 exists (min/add via elementwise builtins, compiler emits pk).
__device__ __forceinline__ R4 quad_rv(float2v sA, float2v sB) {
    const float2v C25  = {25.0f, 25.0f};
    const float2v ONE2 = {1.0f, 1.0f};
    sA = __builtin_elementwise_min(sA, C25);
    sB = __builtin_elementwise_min(sB, C25);
    float2v pA, pB;
    pA.x = __builtin_amdgcn_exp2f(sA.x);
    pA.y = __builtin_amdgcn_exp2f(sA.y);
    pB.x = __builtin_amdgcn_exp2f(sB.x);
    pB.y = __builtin_amdgcn_exp2f(sB.y);
    pA = pA + ONE2;                    // v_pk_add_f32
    pB = pB + ONE2;
    float A = pA.x * pA.y, B = pB.x * pB.y;
    float P = A * B;
    float rp = __builtin_amdgcn_rcpf(P);
    rp = rp * fmaf(-P, rp, 2.0f);      // Newton: ~1 ulp on 1/P
    float rA = rp * B, rB = rp * A;
    R4 r;
    r.a.x = rA * pA.y; r.a.y = rA * pA.x;
    r.b.x = rB * pB.y; r.b.y = rB * pB.x;
    return r;
}

// Split 4 r-values into exact f16 hi (RTZ via cvt_pkrtz) + residual lo*2^11.
// lo computed against the exact f32 value of the STORED f16 (denormal-safe).
__device__ __forceinline__ Act4 split_r4(R4 q) {
    const float2v SC2 = {2048.0f, 2048.0f};
    unsigned hp0 = __builtin_bit_cast(unsigned, __builtin_amdgcn_cvt_pkrtz(q.a.x, q.a.y));
    unsigned hp1 = __builtin_bit_cast(unsigned, __builtin_amdgcn_cvt_pkrtz(q.b.x, q.b.y));
    float2v h0, h1;
    h0.x = (float)__builtin_bit_cast(_Float16, (unsigned short)(hp0 & 0xffffu));
    h0.y = (float)__builtin_bit_cast(_Float16, (unsigned short)(hp0 >> 16));
    h1.x = (float)__builtin_bit_cast(_Float16, (unsigned short)(hp1 & 0xffffu));
    h1.y = (float)__builtin_bit_cast(_Float16, (unsigned short)(hp1 >> 16));
    float2v l0 = (q.a - h0) * SC2;     // v_pk_add(neg) + v_pk_mul, exact
    float2v l1 = (q.b - h1) * SC2;
    Act4 r;
    r.hi01 = hp0; r.hi23 = hp1;
    r.lo01 = __builtin_bit_cast(unsigned, __builtin_amdgcn_cvt_pkrtz(l0.x, l0.y));
    r.lo23 = __builtin_bit_cast(unsigned, __builtin_amdgcn_cvt_pkrtz(l1.x, l1.y));
    return r;
}

// merge hi/lo MFMA outputs (packed fma) -> quad_r
__device__ __forceinline__ R4 merge_quad(floatx4 d, floatx4 e) {
    const float2v UN2 = {UNSC, UNSC};
    float2v d01; d01.x = d[0]; d01.y = d[1];
    float2v d23; d23.x = d[2]; d23.y = d[3];
    float2v e01; e01.x = e[0]; e01.y = e[1];
    float2v e23; e23.x = e[2]; e23.y = e[3];
    float2v s01 = __builtin_elementwise_fma(e01, UN2, d01);  // v_pk_fma_f32
    float2v s23 = __builtin_elementwise_fma(e23, UN2, d23);
    return quad_rv(s01, s23);
}

__device__ __forceinline__ void split_w(float w, float& hi, float& lo) {
    _Float16 h = (_Float16)w;              // RNE
    hi = (float)h;
    lo = (w - hi) * 2048.0f;
}

__global__ __launch_bounds__(256, 4) void cppn_kernel(
    const float* __restrict__ x,
    const float* __restrict__ W0,
    const float* __restrict__ b0,
    const float* __restrict__ Wh,
    const float* __restrict__ bh,
    const float* __restrict__ Wo,
    const float* __restrict__ bo,
    float* __restrict__ out)
{
    const int tid  = threadIdx.x;
    const int lane = tid & 63;
    const int col  = lane & 15;   // MFMA j (point) / A-fragment row i
    const int kg   = lane >> 4;   // k-group 0..3
    const int wib  = tid >> 6;

    // ---- preload hidden weights W' = NSCL*W (hi/lo split) + b' = TSCL*(b + rowsum W)
    // A[i=fo][k=fi]: lane holds i=col, k=kg*4+r  -> Wh[l][col][kg*4+r]
    // C/D[i][j=pt]:  lane holds i=kg*4+r, j=col
    half4   wAhi[NH], wAlo[NH];
    floatx4 bC[NH];
    #pragma unroll
    for (int l = 0; l < NH; ++l) {
        const float* wrow = Wh + l*256 + col*16 + kg*4;
        float w0 = wrow[0], w1 = wrow[1], w2 = wrow[2], w3 = wrow[3];
        // row-sum of row `col` across all 16 k (for the consumer-side bias fold)
        float rs = (w0 + w1) + (w2 + w3);
        rs += __shfl_xor(rs, 16);
        rs += __shfl_xor(rs, 32);
        float h0,h1,h2,h3, lo0,lo1,lo2,lo3;
        split_w(w0*NSCL, h0, lo0);
        split_w(w1*NSCL, h1, lo1);
        split_w(w2*NSCL, h2, lo2);
        split_w(w3*NSCL, h3, lo3);
        uint2v ha, la;
        ha.x = __builtin_bit_cast(unsigned, __builtin_amdgcn_cvt_pkrtz(h0, h1));
        ha.y = __builtin_bit_cast(unsigned, __builtin_amdgcn_cvt_pkrtz(h2, h3));
        la.x = __builtin_bit_cast(unsigned, __builtin_amdgcn_cvt_pkrtz(lo0, lo1));
        la.y = __builtin_bit_cast(unsigned, __builtin_amdgcn_cvt_pkrtz(lo2, lo3));
        wAhi[l] = __builtin_bit_cast(half4, ha);
        wAlo[l] = __builtin_bit_cast(half4, la);
        floatx4 c;
        #pragma unroll
        for (int r = 0; r < 4; ++r) {
            float rs_r = __shfl(rs, kg*4 + r);           // rowsum of row kg*4+r
            c[r] = TSCL * (bh[l*16 + kg*4 + r] + rs_r);
        }
        bC[l] = c;
    }

    // input layer (consumes x directly: plain TSCL scale, no feed-r transform)
    float w0r[4][3]; float b0r[4];
    #pragma unroll
    for (int r = 0; r < 4; ++r) {
        const float* wp = W0 + (kg*4 + r)*3;
        w0r[r][0] = wp[0]*TSCL; w0r[r][1] = wp[1]*TSCL; w0r[r][2] = wp[2]*TSCL;
        b0r[r] = b0[kg*4 + r]*TSCL;
    }

    // output layer: consumes r8 -> wo' = -2*OSCL*wo, bo' = OSCL*(bo + sum wo)
    float woP[4];
    float wsum;
    {
        const float* wp = Wo + kg*4;
        float a = wp[0], b = wp[1], c2 = wp[2], d = wp[3];
        wsum = (a + b) + (c2 + d);
        wsum += __shfl_xor(wsum, 16);
        wsum += __shfl_xor(wsum, 32);
        woP[0] = a*(-2.0f*OSCL); woP[1] = b*(-2.0f*OSCL);
        woP[2] = c2*(-2.0f*OSCL); woP[3] = d*(-2.0f*OSCL);
    }
    const float boP = OSCL * (bo[0] + wsum);

    const floatx4 zeroC = {0.0f, 0.0f, 0.0f, 0.0f};
    const long base0 = ((long)blockIdx.x * 4 + wib) * (64L * CHUNKS);

    #pragma unroll 1
    for (int c = 0; c < CHUNKS; ++c) {
        const long base = base0 + (long)c * 64;

        // ---- input layer -> split r-fragments (4 tiles of 16 points) ----
        half4 hBhi[4], hBlo[4];
        #pragma unroll
        for (int t = 0; t < 4; ++t) {
            const long p = base + t*16 + col;
            const float x0 = x[p*3+0], x1 = x[p*3+1], x2 = x[p*3+2];
            float2v sA, sB;
            sA.x = fmaf(w0r[0][0],x0, fmaf(w0r[0][1],x1, fmaf(w0r[0][2],x2, b0r[0])));
            sA.y = fmaf(w0r[1][0],x0, fmaf(w0r[1][1],x1, fmaf(w0r[1][2],x2, b0r[1])));
            sB.x = fmaf(w0r[2][0],x0, fmaf(w0r[2][1],x1, fmaf(w0r[2][2],x2, b0r[2])));
            sB.y = fmaf(w0r[3][0],x0, fmaf(w0r[3][1],x1, fmaf(w0r[3][2],x2, b0r[3])));
            Act4 a4 = split_r4(quad_rv(sA, sB));
            uint2v hb, lb;
            hb.x = a4.hi01; hb.y = a4.hi23;
            lb.x = a4.lo01; lb.y = a4.lo23;
            hBhi[t] = __builtin_bit_cast(half4, hb);
            hBlo[t] = __builtin_bit_cast(half4, lb);
        }

        // ---- hidden layers 0..6: split MFMA -> merge -> quad-r -> split ----
        #pragma unroll
        for (int l = 0; l < NH-1; ++l) {
            const half4 whi = wAhi[l];
            const half4 wlo = wAlo[l];
            const floatx4 bc = bC[l];
            #pragma unroll
            for (int tp = 0; tp < 2; ++tp) {
                const int u0 = tp*2, u1 = tp*2+1;
                floatx4 d0 = __builtin_amdgcn_mfma_f32_16x16x16f16(whi, hBhi[u0], bc, 0,0,0);
                floatx4 d1 = __builtin_amdgcn_mfma_f32_16x16x16f16(whi, hBhi[u1], bc, 0,0,0);
                floatx4 e0 = __builtin_amdgcn_mfma_f32_16x16x16f16(whi, hBlo[u0], zeroC, 0,0,0);
                floatx4 e1 = __builtin_amdgcn_mfma_f32_16x16x16f16(whi, hBlo[u1], zeroC, 0,0,0);
                e0 = __builtin_amdgcn_mfma_f32_16x16x16f16(wlo, hBhi[u0], e0, 0,0,0);
                e1 = __builtin_amdgcn_mfma_f32_16x16x16f16(wlo, hBhi[u1], e1, 0,0,0);

                Act4 a0 = split_r4(merge_quad(d0, e0));
                Act4 a1 = split_r4(merge_quad(d1, e1));
                uint2v hb0, lb0, hb1, lb1;
                hb0.x = a0.hi01; hb0.y = a0.hi23;
                lb0.x = a0.lo01; lb0.y = a0.lo23;
                hb1.x = a1.hi01; hb1.y = a1.hi23;
                lb1.x = a1.lo01; lb1.y = a1.lo23;
                hBhi[u0] = __builtin_bit_cast(half4, hb0);
                hBlo[u0] = __builtin_bit_cast(half4, lb0);
                hBhi[u1] = __builtin_bit_cast(half4, hb1);
                hBlo[u1] = __builtin_bit_cast(half4, lb1);
            }
        }

        // ---- last hidden layer -> r8 -> output dot (feed-r) + sigmoid ----
        float tot[4];
        #pragma unroll
        for (int t = 0; t < 4; ++t) {
            floatx4 d = __builtin_amdgcn_mfma_f32_16x16x16f16(wAhi[NH-1], hBhi[t], bC[NH-1], 0,0,0);
            floatx4 e = __builtin_amdgcn_mfma_f32_16x16x16f16(wAhi[NH-1], hBlo[t], zeroC, 0,0,0);
            e = __builtin_amdgcn_mfma_f32_16x16x16f16(wAlo[NH-1], hBhi[t], e, 0,0,0);
            R4 r8 = merge_quad(d, e);
            float acc = fmaf(woP[0], r8.a.x,
                        fmaf(woP[1], r8.a.y,
                        fmaf(woP[2], r8.b.x, woP[3] * r8.b.y)));
            acc += __shfl_xor(acc, 16);
            acc += __shfl_xor(acc, 32);
            tot[t] = acc;
        }

        float s = (kg == 0) ? tot[0] : (kg == 1) ? tot[1] : (kg == 2) ? tot[2] : tot[3];
        s += boP;
        float E = __builtin_amdgcn_exp2f(s);
        out[base + lane] = __builtin_amdgcn_rcpf(1.0f + E);
    }
}

extern "C" void kernel_launch(void* const* d_in, const int* in_sizes, int n_in,
                              void* d_out, int out_size, void* d_ws, size_t ws_size,
                              hipStream_t stream) {
    const float* x  = (const float*)d_in[0];
    const float* W0 = (const float*)d_in[1];
    const float* b0 = (const float*)d_in[2];
    const float* Wh = (const float*)d_in[3];
    const float* bh = (const float*)d_in[4];
    const float* Wo = (const float*)d_in[5];
    const float* bo = (const float*)d_in[6];
    float* out = (float*)d_out;

    int n = out_size;                           // 2097152 = 2048 * 1024, exact
    int block = 256;                            // 4 waves
    long ptsPerBlock = 4L * 64 * CHUNKS;        // 1024
    int grid = (int)((n + ptsPerBlock - 1) / ptsPerBlock);   // 2048
    cppn_kernel<<<grid, block, 0, stream>>>(x, W0, b0, Wh, bh, Wo, bo, out);
}

// Round 12
// 107.135 us; speedup vs baseline: 1.0621x; 1.0621x over previous
//
#include <hip/hip_runtime.h>

typedef __attribute__((ext_vector_type(4))) _Float16 half4;
typedef __attribute__((ext_vector_type(8))) _Float16 half8;
typedef __attribute__((ext_vector_type(4))) float floatx4;
typedef __attribute__((ext_vector_type(2))) unsigned uint2v;
typedef __attribute__((ext_vector_type(4))) unsigned uint4v;

#define NH 8
#define CHUNKS 8

struct Split2 { unsigned hi, lo; };

// Split r0,r1 (each in [0,1]) into exact f16 hi (RTZ) + residual lo*2^11.
__device__ __forceinline__ Split2 split2(float t0, float t1) {
    unsigned hp = __builtin_bit_cast(unsigned, __builtin_amdgcn_cvt_pkrtz(t0, t1));
    float h0 = (float)__builtin_bit_cast(_Float16, (unsigned short)(hp & 0xffffu));
    float h1 = (float)__builtin_bit_cast(_Float16, (unsigned short)(hp >> 16));
    float l0 = (t0 - h0) * 2048.0f;
    float l1 = (t1 - h1) * 2048.0f;
    Split2 r;
    r.hi = hp;
    r.lo = __builtin_bit_cast(unsigned, __builtin_amdgcn_cvt_pkrtz(l0, l1));
    return r;
}

// r_i = 1/(2^min(s_i,25) + 1), one v_rcp for 4 activations (no Newton:
// v_rcp_f32 is ~1 ulp; r3 passed at identical absmax with raw rcp).
// s<=25 => p<=2^25+1, P<=~2^100: no overflow. p>=1: no underflow.
__device__ __forceinline__ floatx4 quad_r(float s0, float s1, float s2, float s3) {
    s0 = fminf(s0, 25.0f); s1 = fminf(s1, 25.0f);
    s2 = fminf(s2, 25.0f); s3 = fminf(s3, 25.0f);
    float p0 = __builtin_amdgcn_exp2f(s0) + 1.0f;
    float p1 = __builtin_amdgcn_exp2f(s1) + 1.0f;
    float p2 = __builtin_amdgcn_exp2f(s2) + 1.0f;
    float p3 = __builtin_amdgcn_exp2f(s3) + 1.0f;
    float A = p0 * p1, B = p2 * p3;
    float P = A * B;
    float rp = __builtin_amdgcn_rcpf(P);
    float rA = rp * B, rB = rp * A;
    floatx4 r;
    r[0] = rA * p1; r[1] = rA * p0; r[2] = rB * p3; r[3] = rB * p2;
    return r;
}

__device__ __forceinline__ void split_w(float w, float& hi, float& lo) {
    _Float16 h = (_Float16)w;              // RNE
    hi = (float)h;
    lo = (w - hi) * 2048.0f;
}

__global__ __launch_bounds__(256, 4) void cppn_kernel(
    const float* __restrict__ x,
    const float* __restrict__ W0,
    const float* __restrict__ b0,
    const float* __restrict__ Wh,
    const float* __restrict__ bh,
    const float* __restrict__ Wo,
    const float* __restrict__ bo,
    float* __restrict__ out)
{
    const int tid  = threadIdx.x;
    const int lane = tid & 63;
    const int col  = lane & 15;   // MFMA j (point) / A-fragment row i
    const int kg   = lane >> 4;   // k-group 0..3
    const int wib  = tid >> 6;

    const float TSCL = 2.8853900817779268f;    // 2*log2(e)
    const float NSCL = -2.0f * TSCL;           // feed-r hidden weight scale
    const float OSCL = -1.4426950408889634f;   // -log2(e)
    const float UNSC = 4.8828125e-4f;          // 2^-11

    // ---- preload hidden weights W' = NSCL*W as half8 [hi(4) | lo(4)*2^11]
    //      + b' = TSCL*(b + rowsum W)  (feed-r bias fold)
    // A[i=fo][k=fi]: lane holds i=col, k=kg*4+r  -> Wh[l][col][kg*4+r]
    // C/D[i][j=pt]:  lane holds i=kg*4+r, j=col
    half8   wA8[NH];
    floatx4 bC[NH];
    #pragma unroll
    for (int l = 0; l < NH; ++l) {
        const float* wrow = Wh + l*256 + col*16 + kg*4;
        float w0 = wrow[0], w1 = wrow[1], w2 = wrow[2], w3 = wrow[3];
        // row-sum of row `col` across all 16 k (for the consumer-side bias fold)
        float rs = (w0 + w1) + (w2 + w3);
        rs += __shfl_xor(rs, 16);
        rs += __shfl_xor(rs, 32);
        float h0,h1,h2,h3, lo0,lo1,lo2,lo3;
        split_w(w0*NSCL, h0, lo0);
        split_w(w1*NSCL, h1, lo1);
        split_w(w2*NSCL, h2, lo2);
        split_w(w3*NSCL, h3, lo3);
        uint4v wa;
        wa.x = __builtin_bit_cast(unsigned, __builtin_amdgcn_cvt_pkrtz(h0, h1));
        wa.y = __builtin_bit_cast(unsigned, __builtin_amdgcn_cvt_pkrtz(h2, h3));
        wa.z = __builtin_bit_cast(unsigned, __builtin_amdgcn_cvt_pkrtz(lo0, lo1));
        wa.w = __builtin_bit_cast(unsigned, __builtin_amdgcn_cvt_pkrtz(lo2, lo3));
        wA8[l] = __builtin_bit_cast(half8, wa);
        floatx4 c;
        #pragma unroll
        for (int r = 0; r < 4; ++r) {
            float rs_r = __shfl(rs, kg*4 + r);           // rowsum of row kg*4+r
            c[r] = TSCL * (bh[l*16 + kg*4 + r] + rs_r);
        }
        bC[l] = c;
    }

    // input layer (consumes x directly: plain TSCL scale, no feed-r transform)
    float w0r[4][3]; float b0r[4];
    #pragma unroll
    for (int r = 0; r < 4; ++r) {
        const float* wp = W0 + (kg*4 + r)*3;
        w0r[r][0] = wp[0]*TSCL; w0r[r][1] = wp[1]*TSCL; w0r[r][2] = wp[2]*TSCL;
        b0r[r] = b0[kg*4 + r]*TSCL;
    }

    // output layer: consumes r8 -> wo' = -2*OSCL*wo, bo' = OSCL*(bo + sum wo)
    float woP[4];
    float wsum;
    {
        const float* wp = Wo + kg*4;
        float a = wp[0], b = wp[1], c2 = wp[2], d = wp[3];
        wsum = (a + b) + (c2 + d);
        wsum += __shfl_xor(wsum, 16);
        wsum += __shfl_xor(wsum, 32);
        woP[0] = a*(-2.0f*OSCL); woP[1] = b*(-2.0f*OSCL);
        woP[2] = c2*(-2.0f*OSCL); woP[3] = d*(-2.0f*OSCL);
    }
    const float boP = OSCL * (bo[0] + wsum);

    const floatx4 zeroC = {0.0f, 0.0f, 0.0f, 0.0f};
    const int base0 = (blockIdx.x * 4 + wib) * (64 * CHUNKS);

    #pragma unroll 1
    for (int c = 0; c < CHUNKS; ++c) {
        const int base = base0 + c * 64;

        // ---- input layer -> split r-fragments (4 tiles of 16 points) ----
        half4 hBhi[4], hBlo[4];
        #pragma unroll
        for (int t = 0; t < 4; ++t) {
            const int p = base + t*16 + col;
            const float x0 = x[p*3+0], x1 = x[p*3+1], x2 = x[p*3+2];
            float a0 = fmaf(w0r[0][0],x0, fmaf(w0r[0][1],x1, fmaf(w0r[0][2],x2, b0r[0])));
            float a1 = fmaf(w0r[1][0],x0, fmaf(w0r[1][1],x1, fmaf(w0r[1][2],x2, b0r[1])));
            float a2 = fmaf(w0r[2][0],x0, fmaf(w0r[2][1],x1, fmaf(w0r[2][2],x2, b0r[2])));
            float a3 = fmaf(w0r[3][0],x0, fmaf(w0r[3][1],x1, fmaf(w0r[3][2],x2, b0r[3])));
            floatx4 rq = quad_r(a0, a1, a2, a3);
            Split2 p01 = split2(rq[0], rq[1]);
            Split2 p23 = split2(rq[2], rq[3]);
            uint2v hb, lb;
            hb.x = p01.hi; hb.y = p23.hi;
            lb.x = p01.lo; lb.y = p23.lo;
            hBhi[t] = __builtin_bit_cast(half4, hb);
            hBlo[t] = __builtin_bit_cast(half4, lb);
        }

        // ---- hidden layers 0..6: d = Whi*Hhi + b (K=16);
        //      e = Whi*Hlo + Wlo*Hhi in ONE K=32 MFMA with A=[Whi|Wlo], B=[Hlo|Hhi]
        #pragma unroll
        for (int l = 0; l < NH-1; ++l) {
            const half8 wa8 = wA8[l];
            const uint4v wau = __builtin_bit_cast(uint4v, wa8);
            uint2v whu; whu.x = wau.x; whu.y = wau.y;
            const half4 whi = __builtin_bit_cast(half4, whu);
            const floatx4 bc = bC[l];
            #pragma unroll
            for (int tp = 0; tp < 2; ++tp) {
                const int u0 = tp*2, u1 = tp*2+1;
                const uint2v hbu0 = __builtin_bit_cast(uint2v, hBhi[u0]);
                const uint2v lbu0 = __builtin_bit_cast(uint2v, hBlo[u0]);
                const uint2v hbu1 = __builtin_bit_cast(uint2v, hBhi[u1]);
                const uint2v lbu1 = __builtin_bit_cast(uint2v, hBlo[u1]);
                uint4v b0v, b1v;
                b0v.x = lbu0.x; b0v.y = lbu0.y; b0v.z = hbu0.x; b0v.w = hbu0.y;
                b1v.x = lbu1.x; b1v.y = lbu1.y; b1v.z = hbu1.x; b1v.w = hbu1.y;
                floatx4 d0 = __builtin_amdgcn_mfma_f32_16x16x16f16(whi, hBhi[u0], bc, 0,0,0);
                floatx4 d1 = __builtin_amdgcn_mfma_f32_16x16x16f16(whi, hBhi[u1], bc, 0,0,0);
                floatx4 e0 = __builtin_amdgcn_mfma_f32_16x16x32_f16(wa8, __builtin_bit_cast(half8, b0v), zeroC, 0,0,0);
                floatx4 e1 = __builtin_amdgcn_mfma_f32_16x16x32_f16(wa8, __builtin_bit_cast(half8, b1v), zeroC, 0,0,0);

                floatx4 q0 = quad_r(fmaf(e0[0], UNSC, d0[0]),
                                    fmaf(e0[1], UNSC, d0[1]),
                                    fmaf(e0[2], UNSC, d0[2]),
                                    fmaf(e0[3], UNSC, d0[3]));
                floatx4 q1 = quad_r(fmaf(e1[0], UNSC, d1[0]),
                                    fmaf(e1[1], UNSC, d1[1]),
                                    fmaf(e1[2], UNSC, d1[2]),
                                    fmaf(e1[3], UNSC, d1[3]));
                Split2 a01 = split2(q0[0], q0[1]);
                Split2 a23 = split2(q0[2], q0[3]);
                Split2 b01 = split2(q1[0], q1[1]);
                Split2 b23 = split2(q1[2], q1[3]);
                uint2v hb0, lb0, hb1, lb1;
                hb0.x = a01.hi; hb0.y = a23.hi;
                lb0.x = a01.lo; lb0.y = a23.lo;
                hb1.x = b01.hi; hb1.y = b23.hi;
                lb1.x = b01.lo; lb1.y = b23.lo;
                hBhi[u0] = __builtin_bit_cast(half4, hb0);
                hBlo[u0] = __builtin_bit_cast(half4, lb0);
                hBhi[u1] = __builtin_bit_cast(half4, hb1);
                hBlo[u1] = __builtin_bit_cast(half4, lb1);
            }
        }

        // ---- last hidden layer -> r8 -> output dot (feed-r) + sigmoid ----
        float tot[4];
        {
            const half8 wa8 = wA8[NH-1];
            const uint4v wau = __builtin_bit_cast(uint4v, wa8);
            uint2v whu; whu.x = wau.x; whu.y = wau.y;
            const half4 whi = __builtin_bit_cast(half4, whu);
            const floatx4 bc = bC[NH-1];
            #pragma unroll
            for (int t = 0; t < 4; ++t) {
                const uint2v hbu = __builtin_bit_cast(uint2v, hBhi[t]);
                const uint2v lbu = __builtin_bit_cast(uint2v, hBlo[t]);
                uint4v bv;
                bv.x = lbu.x; bv.y = lbu.y; bv.z = hbu.x; bv.w = hbu.y;
                floatx4 d = __builtin_amdgcn_mfma_f32_16x16x16f16(whi, hBhi[t], bc, 0,0,0);
                floatx4 e = __builtin_amdgcn_mfma_f32_16x16x32_f16(wa8, __builtin_bit_cast(half8, bv), zeroC, 0,0,0);
                floatx4 r8 = quad_r(fmaf(e[0], UNSC, d[0]),
                                    fmaf(e[1], UNSC, d[1]),
                                    fmaf(e[2], UNSC, d[2]),
                                    fmaf(e[3], UNSC, d[3]));
                float acc = fmaf(woP[0], r8[0],
                            fmaf(woP[1], r8[1],
                            fmaf(woP[2], r8[2], woP[3] * r8[3])));
                acc += __shfl_xor(acc, 16);
                acc += __shfl_xor(acc, 32);
                tot[t] = acc;
            }
        }

        float s = (kg == 0) ? tot[0] : (kg == 1) ? tot[1] : (kg == 2) ? tot[2] : tot[3];
        s += boP;
        float E = __builtin_amdgcn_exp2f(s);
        out[base + lane] = __builtin_amdgcn_rcpf(1.0f + E);
    }
}

extern "C" void kernel_launch(void* const* d_in, const int* in_sizes, int n_in,
                              void* d_out, int out_size, void* d_ws, size_t ws_size,
                              hipStream_t stream) {
    const float* x  = (const float*)d_in[0];
    const float* W0 = (const float*)d_in[1];
    const float* b0 = (const float*)d_in[2];
    const float* Wh = (const float*)d_in[3];
    const float* bh = (const float*)d_in[4];
    const float* Wo = (const float*)d_in[5];
    const float* bo = (const float*)d_in[6];
    float* out = (float*)d_out;

    int n = out_size;                           // 2097152 = 1024 * 2048, exact
    int block = 256;                            // 4 waves
    long ptsPerBlock = 4L * 64 * CHUNKS;        // 2048
    int grid = (int)((n + ptsPerBlock - 1) / ptsPerBlock);   // 1024
    cppn_kernel<<<grid, block, 0, stream>>>(x, W0, b0, Wh, bh, Wo, bo, out);
}